// Round 6
// baseline (433.276 us; speedup 1.0000x reference)
//
#include <hip/hip_runtime.h>
#include <math.h>

// Problem constants (VQ2): B=16384, D_IN=512, H=64, C=256, K=2048
#define NB 16384
#define NDIN 512
#define NH 64
#define NC 256
#define NK 2048

typedef __bf16 bf16;
typedef __bf16 bf16x4 __attribute__((ext_vector_type(4)));
typedef __bf16 bf16x8 __attribute__((ext_vector_type(8)));
typedef float f32x4 __attribute__((ext_vector_type(4)));

__device__ __forceinline__ void gload_lds16(const bf16* g, bf16* l) {
  __builtin_amdgcn_global_load_lds(
      (const __attribute__((address_space(1))) void*)g,
      (__attribute__((address_space(3))) void*)l, 16, 0, 0);
}

// ---------------------------------------------------------------------------
// All four weight transpose+casts in one kernel.  Wt[n][k] = (bf16)W[k][n].
// ---------------------------------------------------------------------------
__global__ __launch_bounds__(256) void weight_prep(
    const float* __restrict__ We, const float* __restrict__ W0,
    const float* __restrict__ W1, const float* __restrict__ Wmu,
    bf16* __restrict__ weT, bf16* __restrict__ w0T,
    bf16* __restrict__ w1T, bf16* __restrict__ wmuT) {
  int i = blockIdx.x * 256 + threadIdx.x;
  if (i < NH * NDIN) {  // weT [64][512] from We[512][64]
    int n = i >> 9, k = i & 511;
    weT[i] = (bf16)We[k * NH + n];
    return;
  }
  i -= NH * NDIN;
  if (i < NH * NH) {  // w0T [64][64]
    int n = i >> 6, k = i & 63;
    w0T[i] = (bf16)W0[k * NH + n];
    return;
  }
  i -= NH * NH;
  if (i < NC * NH) {  // w1T [256][64] from W1[64][256]
    int n = i >> 6, k = i & 63;
    w1T[i] = (bf16)W1[k * NC + n];
    return;
  }
  i -= NC * NH;
  if (i < NC * NC) {  // wmuT [256][256]
    int n = i >> 8, k = i & 255;
    wmuT[i] = (bf16)Wmu[k * NC + n];
  }
}

// ---------------------------------------------------------------------------
// protos fp32 [NK][NC] -> bf16 + pn (norm of ROUNDED values); one wave/row
// ---------------------------------------------------------------------------
__global__ __launch_bounds__(256) void cast_protos(const float* __restrict__ P,
                                                   bf16* __restrict__ Pb,
                                                   float* __restrict__ pn) {
  int wave = (int)((blockIdx.x * 256 + threadIdx.x) >> 6);
  int lane = threadIdx.x & 63;
  if (wave >= NK) return;
  float4 v = ((const float4*)(P + (size_t)wave * NC))[lane];
  bf16x4 o;
  o[0] = (bf16)v.x; o[1] = (bf16)v.y; o[2] = (bf16)v.z; o[3] = (bf16)v.w;
  ((bf16x4*)(Pb + (size_t)wave * NC))[lane] = o;
  float s = 0.f;
#pragma unroll
  for (int j = 0; j < 4; ++j) {
    float f = (float)o[j];
    s = fmaf(f, f, s);
  }
  for (int off = 32; off > 0; off >>= 1) s += __shfl_xor(s, off);
  if (lane == 0) pn[wave] = s;
}

// ---------------------------------------------------------------------------
// Fully fused 4-layer MLP + rn + colsum.  Block = 16 rows, 4 waves.
// ---------------------------------------------------------------------------
__global__ __launch_bounds__(256) void fused_mlp(
    const float* __restrict__ x, const bf16* __restrict__ weT,
    const bf16* __restrict__ w0T, const bf16* __restrict__ w1T,
    const bf16* __restrict__ wmuT,
    const float* __restrict__ b_emb, const float* __restrict__ b0,
    const float* __restrict__ b1, const float* __restrict__ b_mu,
    bf16* __restrict__ mub, float* __restrict__ rn,
    float* __restrict__ colsum) {
  __shared__ __align__(16) bf16 Xs[16 * 520];
  __shared__ __align__(16) bf16 H0[16 * 72];
  __shared__ __align__(16) bf16 H1[16 * 72];
  __shared__ __align__(16) bf16 H2[16 * 264];
  __shared__ float Rr[4][16];
  const int t = threadIdx.x, w = t >> 6, lane = t & 63;
  const int lm = lane & 15, kq = lane >> 4;
  const int bm = blockIdx.x * 16;
#pragma unroll
  for (int i = 0; i < 8; ++i) {
    int c = i * 256 + t;
    int row = c >> 7, off = c & 127;
    float4 v = *(const float4*)&x[(size_t)(bm + row) * NDIN + off * 4];
    bf16x4 o;
    o[0] = (bf16)v.x; o[1] = (bf16)v.y; o[2] = (bf16)v.z; o[3] = (bf16)v.w;
    *(bf16x4*)&Xs[row * 520 + off * 4] = o;
  }
  __syncthreads();
  f32x4 c0 = {};
#pragma unroll
  for (int kc = 0; kc < 16; ++kc) {
    bf16x8 a = *(const bf16x8*)&Xs[lm * 520 + kc * 32 + kq * 8];
    bf16x8 b = *(const bf16x8*)&weT[(size_t)(w * 16 + lm) * NDIN + kc * 32 + kq * 8];
    c0 = __builtin_amdgcn_mfma_f32_16x16x32_bf16(a, b, c0, 0, 0, 0);
  }
  {
    const float bv = b_emb[w * 16 + lm];
#pragma unroll
    for (int rg = 0; rg < 4; ++rg)
      H0[(kq * 4 + rg) * 72 + w * 16 + lm] = (bf16)(c0[rg] + bv);
  }
  __syncthreads();
  f32x4 c1 = {};
#pragma unroll
  for (int kc = 0; kc < 2; ++kc) {
    bf16x8 a = *(const bf16x8*)&H0[lm * 72 + kc * 32 + kq * 8];
    bf16x8 b = *(const bf16x8*)&w0T[(size_t)(w * 16 + lm) * NH + kc * 32 + kq * 8];
    c1 = __builtin_amdgcn_mfma_f32_16x16x32_bf16(a, b, c1, 0, 0, 0);
  }
  {
    const float bv = b0[w * 16 + lm];
#pragma unroll
    for (int rg = 0; rg < 4; ++rg)
      H1[(kq * 4 + rg) * 72 + w * 16 + lm] = (bf16)fmaxf(c1[rg] + bv, 0.f);
  }
  __syncthreads();
  f32x4 c2[4] = {};
#pragma unroll
  for (int kc = 0; kc < 2; ++kc) {
    bf16x8 a = *(const bf16x8*)&H1[lm * 72 + kc * 32 + kq * 8];
#pragma unroll
    for (int ni = 0; ni < 4; ++ni) {
      bf16x8 b = *(const bf16x8*)&w1T[(size_t)(w * 64 + ni * 16 + lm) * NH + kc * 32 + kq * 8];
      c2[ni] = __builtin_amdgcn_mfma_f32_16x16x32_bf16(a, b, c2[ni], 0, 0, 0);
    }
  }
#pragma unroll
  for (int ni = 0; ni < 4; ++ni) {
    const float bv = b1[w * 64 + ni * 16 + lm];
#pragma unroll
    for (int rg = 0; rg < 4; ++rg)
      H2[(kq * 4 + rg) * 264 + w * 64 + ni * 16 + lm] = (bf16)fmaxf(c2[ni][rg] + bv, 0.f);
  }
  __syncthreads();
  f32x4 c3[4] = {};
#pragma unroll
  for (int kc = 0; kc < 8; ++kc) {
    bf16x8 a = *(const bf16x8*)&H2[lm * 264 + kc * 32 + kq * 8];
#pragma unroll
    for (int ni = 0; ni < 4; ++ni) {
      bf16x8 b = *(const bf16x8*)&wmuT[(size_t)(w * 64 + ni * 16 + lm) * NC + kc * 32 + kq * 8];
      c3[ni] = __builtin_amdgcn_mfma_f32_16x16x32_bf16(a, b, c3[ni], 0, 0, 0);
    }
  }
  // epilogue: store bf16 mu + fused row-norm (of ROUNDED values) + colsum
  float rpart[4] = {0.f, 0.f, 0.f, 0.f};
  float cpart[4] = {0.f, 0.f, 0.f, 0.f};
#pragma unroll
  for (int ni = 0; ni < 4; ++ni) {
    const int col = w * 64 + ni * 16 + lm;
    const float bv = b_mu[col];
#pragma unroll
    for (int rg = 0; rg < 4; ++rg) {
      bf16 q = (bf16)(c3[ni][rg] + bv);
      mub[(size_t)(bm + kq * 4 + rg) * NC + col] = q;
      float f = (float)q;
      rpart[rg] = fmaf(f, f, rpart[rg]);
      cpart[ni] += f;
    }
  }
#pragma unroll
  for (int off = 1; off < 16; off <<= 1)
#pragma unroll
    for (int rg = 0; rg < 4; ++rg) rpart[rg] += __shfl_xor(rpart[rg], off);
  if (lm == 0)
#pragma unroll
    for (int rg = 0; rg < 4; ++rg) Rr[w][kq * 4 + rg] = rpart[rg];
  // colsum: reduce over kq lanes (rows), then one atomic per column
#pragma unroll
  for (int off = 16; off < 64; off <<= 1)
#pragma unroll
    for (int ni = 0; ni < 4; ++ni) cpart[ni] += __shfl_xor(cpart[ni], off);
  if (kq == 0)
#pragma unroll
    for (int ni = 0; ni < 4; ++ni)
      atomicAdd(&colsum[w * 64 + ni * 16 + lm], cpart[ni]);
  __syncthreads();
  if (t < 16) rn[bm + t] = Rr[0][t] + Rr[1][t] + Rr[2][t] + Rr[3][t];
}

// ---------------------------------------------------------------------------
// Pass 1: GEMM tile (128x128) -> v = 2*mu·p - pn (rn dropped: row-constant).
//   argmax(v+gumbel) via packed u64 atomicMax; Zpart[row] += sum exp(v).
//   No S materialization.  exp needs no max-subtract: s<=~0, |s| tiny.
// ---------------------------------------------------------------------------
__global__ __launch_bounds__(256) void gemm_pass1(
    const bf16* __restrict__ A, const bf16* __restrict__ Bt,
    const float* __restrict__ pn, const float* __restrict__ gum,
    float* __restrict__ Zpart, unsigned long long* __restrict__ packed) {
  __shared__ __align__(16) bf16 As[128 * 32];
  __shared__ __align__(16) bf16 Bs[128 * 32];
  const int t = threadIdx.x;
  const int w = t >> 6, lane = t & 63;
  const int bm = blockIdx.x * 128, bn = blockIdx.y * 128;
  const int wm = (w >> 1) * 64, wn = (w & 1) * 64;
  const int lm = lane & 15, kq = lane >> 4;
  const int xorc = (lm & 3) ^ ((lm >> 2) & 3);
  const int pc8 = (kq ^ xorc) << 3;
  f32x4 acc[4][4] = {};
  for (int k0 = 0; k0 < NC; k0 += 32) {
    __syncthreads();
#pragma unroll
    for (int i = 0; i < 2; ++i) {
      int c = i * 256 + t;
      int r = c >> 2, sg = c & 3;
      int kc = sg ^ (r & 3) ^ ((r >> 2) & 3);
      gload_lds16(&A[(size_t)(bm + r) * NC + k0 + kc * 8], &As[c * 8]);
      gload_lds16(&Bt[(size_t)(bn + r) * NC + k0 + kc * 8], &Bs[c * 8]);
    }
    __syncthreads();
    bf16x8 a[4], b[4];
#pragma unroll
    for (int i = 0; i < 4; ++i) {
      a[i] = *(const bf16x8*)&As[(wm + i * 16 + lm) * 32 + pc8];
      b[i] = *(const bf16x8*)&Bs[(wn + i * 16 + lm) * 32 + pc8];
    }
#pragma unroll
    for (int mi = 0; mi < 4; ++mi)
#pragma unroll
      for (int ni = 0; ni < 4; ++ni)
        acc[mi][ni] = __builtin_amdgcn_mfma_f32_16x16x32_bf16(a[mi], b[ni], acc[mi][ni], 0, 0, 0);
  }
  float pnv[4];
#pragma unroll
  for (int ni = 0; ni < 4; ++ni) pnv[ni] = pn[bn + wn + ni * 16 + lm];
#pragma unroll
  for (int mi = 0; mi < 4; ++mi) {
    const int row0 = bm + wm + mi * 16 + kq * 4;
    float g[4][4];
#pragma unroll
    for (int rg = 0; rg < 4; ++rg)
#pragma unroll
      for (int ni = 0; ni < 4; ++ni)
        g[rg][ni] = gum[(size_t)(row0 + rg) * NK + bn + wn + ni * 16 + lm];
    float zs[4];
    unsigned long long best[4];
#pragma unroll
    for (int rg = 0; rg < 4; ++rg) {
      float z = 0.f;
      unsigned long long bb = 0ull;
#pragma unroll
      for (int ni = 0; ni < 4; ++ni) {
        const int col = bn + wn + ni * 16 + lm;
        float v = 2.f * acc[mi][ni][rg] - pnv[ni];
        z += expf(v);
        float vg = v + g[rg][ni];
        unsigned kb = __float_as_uint(vg);
        kb = (kb & 0x80000000u) ? ~kb : (kb | 0x80000000u);
        unsigned long long pk =
            ((unsigned long long)kb << 32) | (unsigned)(~(unsigned)col);
        if (pk > bb) bb = pk;
      }
      zs[rg] = z;
      best[rg] = bb;
    }
#pragma unroll
    for (int off = 1; off < 16; off <<= 1) {
#pragma unroll
      for (int rg = 0; rg < 4; ++rg) {
        zs[rg] += __shfl_xor(zs[rg], off);
        unsigned lo = (unsigned)best[rg], hi = (unsigned)(best[rg] >> 32);
        unsigned olo = __shfl_xor(lo, off), ohi = __shfl_xor(hi, off);
        unsigned long long o = ((unsigned long long)ohi << 32) | olo;
        if (o > best[rg]) best[rg] = o;
      }
    }
    if (lm == 0) {
#pragma unroll
      for (int rg = 0; rg < 4; ++rg) {
        atomicAdd(&Zpart[row0 + rg], zs[rg]);
        atomicMax(&packed[row0 + rg], best[rg]);
      }
    }
  }
}

// ---------------------------------------------------------------------------
// Pass 2: same GEMM; csp[col] += sum_rows exp(v)/Zpart[row].
// ---------------------------------------------------------------------------
__global__ __launch_bounds__(256) void gemm_pass2(
    const bf16* __restrict__ A, const bf16* __restrict__ Bt,
    const float* __restrict__ pn, const float* __restrict__ Zpart,
    float* __restrict__ csp) {
  __shared__ __align__(16) bf16 As[128 * 32];
  __shared__ __align__(16) bf16 Bs[128 * 32];
  const int t = threadIdx.x;
  const int w = t >> 6, lane = t & 63;
  const int bm = blockIdx.x * 128, bn = blockIdx.y * 128;
  const int wm = (w >> 1) * 64, wn = (w & 1) * 64;
  const int lm = lane & 15, kq = lane >> 4;
  const int xorc = (lm & 3) ^ ((lm >> 2) & 3);
  const int pc8 = (kq ^ xorc) << 3;
  f32x4 acc[4][4] = {};
  for (int k0 = 0; k0 < NC; k0 += 32) {
    __syncthreads();
#pragma unroll
    for (int i = 0; i < 2; ++i) {
      int c = i * 256 + t;
      int r = c >> 2, sg = c & 3;
      int kc = sg ^ (r & 3) ^ ((r >> 2) & 3);
      gload_lds16(&A[(size_t)(bm + r) * NC + k0 + kc * 8], &As[c * 8]);
      gload_lds16(&Bt[(size_t)(bn + r) * NC + k0 + kc * 8], &Bs[c * 8]);
    }
    __syncthreads();
    bf16x8 a[4], b[4];
#pragma unroll
    for (int i = 0; i < 4; ++i) {
      a[i] = *(const bf16x8*)&As[(wm + i * 16 + lm) * 32 + pc8];
      b[i] = *(const bf16x8*)&Bs[(wn + i * 16 + lm) * 32 + pc8];
    }
#pragma unroll
    for (int mi = 0; mi < 4; ++mi)
#pragma unroll
      for (int ni = 0; ni < 4; ++ni)
        acc[mi][ni] = __builtin_amdgcn_mfma_f32_16x16x32_bf16(a[mi], b[ni], acc[mi][ni], 0, 0, 0);
  }
  float pnv[4];
#pragma unroll
  for (int ni = 0; ni < 4; ++ni) pnv[ni] = pn[bn + wn + ni * 16 + lm];
  float iz[4][4];
#pragma unroll
  for (int mi = 0; mi < 4; ++mi)
#pragma unroll
    for (int rg = 0; rg < 4; ++rg)
      iz[mi][rg] = 1.f / Zpart[bm + wm + mi * 16 + kq * 4 + rg];
  float cpart[4] = {0.f, 0.f, 0.f, 0.f};
#pragma unroll
  for (int mi = 0; mi < 4; ++mi)
#pragma unroll
    for (int ni = 0; ni < 4; ++ni)
#pragma unroll
      for (int rg = 0; rg < 4; ++rg)
        cpart[ni] += expf(2.f * acc[mi][ni][rg] - pnv[ni]) * iz[mi][rg];
  // reduce over kq lanes (rows), then one atomic per column
#pragma unroll
  for (int off = 16; off < 64; off <<= 1)
#pragma unroll
    for (int ni = 0; ni < 4; ++ni) cpart[ni] += __shfl_xor(cpart[ni], off);
  if (kq == 0)
#pragma unroll
    for (int ni = 0; ni < 4; ++ni)
      atomicAdd(&csp[bn + wn + ni * 16 + lm], cpart[ni]);
}

// ---------------------------------------------------------------------------
// Gather: out[b,:] = protos[argmax[b],:]  (exact fp32 copy)
// ---------------------------------------------------------------------------
__global__ __launch_bounds__(256) void gather_out(
    const unsigned long long* __restrict__ packed,
    const float* __restrict__ protos, float* __restrict__ out) {
  const int t = threadIdx.x, w = t >> 6, lane = t & 63;
#pragma unroll
  for (int rr = 0; rr < 4; ++rr) {
    const int b = blockIdx.x * 16 + w * 4 + rr;
    const unsigned col = ~(unsigned)(packed[b] & 0xffffffffull);
    ((float4*)(out + (size_t)b * NC))[lane] =
        ((const float4*)(protos + (size_t)col * NC))[lane];
  }
}

// ---------------------------------------------------------------------------
// Finalize: mlsum = sum_b (log Zpart_b - rn_b); closed-form csl; loss.
// ---------------------------------------------------------------------------
__global__ __launch_bounds__(256) void finalize_v3(
    const float* __restrict__ csp, const float* __restrict__ colsum,
    const bf16* __restrict__ pb, const float* __restrict__ pn,
    const float* __restrict__ rn, const float* __restrict__ Zpart,
    float* __restrict__ out_loss) {
  const int t = threadIdx.x;
  __shared__ double sd[256];
  __shared__ float cs[256];
  double rs = 0.0, ls = 0.0;
  for (int i = t; i < NB; i += 256) {
    rs += (double)rn[i];
    ls += (double)logf(Zpart[i]);
  }
  cs[t] = colsum[t];
  sd[t] = rs;
  __syncthreads();
  for (int off = 128; off > 0; off >>= 1) {
    if (t < off) sd[t] += sd[t + off];
    __syncthreads();
  }
  const double rnsum = sd[0];
  __syncthreads();
  sd[t] = ls;
  __syncthreads();
  for (int off = 128; off > 0; off >>= 1) {
    if (t < off) sd[t] += sd[t + off];
    __syncthreads();
  }
  const double mlsum = sd[0] - rnsum;  // sum_b (log Zpart - rn)
  __syncthreads();
  double cap = 0.0, plp = 0.0;
  for (int k = t; k < NK; k += 256) {
    const bf16* pr = pb + (size_t)k * NC;
    float dot = 0.f;
    for (int c = 0; c < NC; c += 8) {
      bf16x8 v = *(const bf16x8*)&pr[c];
#pragma unroll
      for (int e = 0; e < 8; ++e) dot = fmaf(cs[c + e], (float)v[e], dot);
    }
    double csl = 2.0 * (double)dot - rnsum - (double)NB * (double)pn[k] - mlsum;
    double mlp = csl * (1.0 / (double)NB);
    double prior = (double)csp[k] * (1.0 / (double)NB) + 1e-6;
    double lp = log(prior);
    cap += prior * (lp - mlp);
    plp += prior * lp;
  }
  sd[t] = cap;
  __syncthreads();
  for (int off = 128; off > 0; off >>= 1) {
    if (t < off) sd[t] += sd[t + off];
    __syncthreads();
  }
  const double capT = sd[0];
  __syncthreads();
  sd[t] = plp;
  __syncthreads();
  for (int off = 128; off > 0; off >>= 1) {
    if (t < off) sd[t] += sd[t + off];
    __syncthreads();
  }
  if (t == 0) out_loss[0] = (float)(0.01 * capT + 0.001 * sd[0]);
}

// ---------------------------------------------------------------------------
extern "C" void kernel_launch(void* const* d_in, const int* in_sizes, int n_in,
                              void* d_out, int out_size, void* d_ws, size_t ws_size,
                              hipStream_t stream) {
  const float* x = (const float*)d_in[0];
  const float* gumbel = (const float*)d_in[1];
  const float* W_emb = (const float*)d_in[2];
  const float* b_emb = (const float*)d_in[3];
  const float* W0 = (const float*)d_in[4];
  const float* b0 = (const float*)d_in[5];
  const float* W1 = (const float*)d_in[6];
  const float* b1 = (const float*)d_in[7];
  const float* W_mu = (const float*)d_in[8];
  const float* b_mu = (const float*)d_in[9];
  // d_in[10]=W_var, d_in[11]=b_var unused (logvar dead downstream)
  const float* protos = (const float*)d_in[12];
  float* out = (float*)d_out;

  // workspace layout (no S buffer anymore)
  float* rn = (float*)d_ws;                                   // [NB]
  float* pn = rn + NB;                                        // [NK]
  float* Zpart = pn + NK;                                     // [NB]  (zeroed)
  float* csp = Zpart + NB;                                    // [NK]  (zeroed)
  float* colsum = csp + NK;                                   // [NC]  (zeroed)
  unsigned long long* packed = (unsigned long long*)(colsum + NC);  // [NB] (zeroed)
  bf16* mub = (bf16*)(packed + NB);                           // [NB][NC]
  bf16* pb = mub + (size_t)NB * NC;                           // [NK][NC]
  bf16* weT = pb + (size_t)NK * NC;                           // [NH][NDIN]
  bf16* w0T = weT + NH * NDIN;                                // [NH][NH]
  bf16* w1T = w0T + NH * NH;                                  // [NC][NH]
  bf16* wmuT = w1T + NC * NH;                                 // [NC][NC]

  hipMemsetAsync(Zpart, 0,
                 (NB + NK + NC) * sizeof(float) + NB * sizeof(unsigned long long),
                 stream);

  dim3 blk(256);
  const int wp_elems = NH * NDIN + NH * NH + NC * NH + NC * NC;
  weight_prep<<<(wp_elems + 255) / 256, blk, 0, stream>>>(W_emb, W0, W1, W_mu,
                                                          weT, w0T, w1T, wmuT);
  cast_protos<<<NK / 4, blk, 0, stream>>>(protos, pb, pn);

  fused_mlp<<<NB / 16, blk, 0, stream>>>(x, weT, w0T, w1T, wmuT,
                                         b_emb, b0, b1, b_mu, mub, rn, colsum);

  gemm_pass1<<<dim3(NB / 128, NK / 128), blk, 0, stream>>>(mub, pb, pn, gumbel,
                                                           Zpart, packed);
  gather_out<<<NB / 16, blk, 0, stream>>>(packed, protos, out);
  gemm_pass2<<<dim3(NB / 128, NK / 128), blk, 0, stream>>>(mub, pb, pn, Zpart, csp);
  finalize_v3<<<1, blk, 0, stream>>>(csp, colsum, pb, pn, rn, Zpart,
                                     out + (size_t)NB * NC);
}